// Round 1
// baseline (262.589 us; speedup 1.0000x reference)
//
#include <hip/hip_runtime.h>

typedef short bf16x8 __attribute__((ext_vector_type(8)));
typedef float f32x4 __attribute__((ext_vector_type(4)));

__device__ __forceinline__ unsigned short f2bf(float f) {
    union { float f; unsigned u; } v; v.f = f;
    unsigned r = v.u + 0x7fffu + ((v.u >> 16) & 1u);
    return (unsigned short)(r >> 16);
}

// ---------------------------------------------------------------------------
// Transpose + fp32->bf16 convert:  in[K][N] fp32  ->  out[N][K] bf16
// ---------------------------------------------------------------------------
__global__ __launch_bounds__(256) void transpose_w(const float* __restrict__ in,
                                                   unsigned short* __restrict__ out,
                                                   int K, int N) {
    __shared__ float tile[32][33];
    const int n0 = blockIdx.x * 32, k0 = blockIdx.y * 32;
    const int tx = threadIdx.x, ty = threadIdx.y;
#pragma unroll
    for (int i = 0; i < 32; i += 8)
        tile[ty + i][tx] = in[(size_t)(k0 + ty + i) * N + n0 + tx];
    __syncthreads();
#pragma unroll
    for (int i = 0; i < 32; i += 8)
        out[(size_t)(n0 + ty + i) * K + k0 + tx] = f2bf(tile[tx][ty + i]);
}

// ---------------------------------------------------------------------------
// GEMM  C[M,N] = A[M,K] * Bt[N,K]^T + bias
// 128x128 tile, 4 waves (2x2 of 64x64), BK=32, mfma_f32_16x16x32_bf16.
// AF32: A is fp32 (convert during staging); else A is bf16 (ushort).
// OUTMODE 0: scatter to Q/K/V [B,H,T,D] bf16 (+bias). OUTMODE 1: fp32 C (+bias).
// ---------------------------------------------------------------------------
template <bool AF32, int OUTMODE>
__global__ __launch_bounds__(256) void gemm_bt_kernel(
    const void* __restrict__ Ap, const unsigned short* __restrict__ Bt,
    const float* __restrict__ bias, float* __restrict__ Cf,
    unsigned short* __restrict__ Qo, unsigned short* __restrict__ Ko,
    unsigned short* __restrict__ Vo, int M, int N, int K) {
    __shared__ __align__(16) unsigned short lA[128][40];  // padded: 80B row stride
    __shared__ __align__(16) unsigned short lB[128][40];

    const int tid = threadIdx.x;
    const int lane = tid & 63, wid = tid >> 6;
    const int wr = wid >> 1, wc = wid & 1;
    const int fr = lane & 15, fq = lane >> 4;
    const int m0 = blockIdx.y * 128, n0 = blockIdx.x * 128;
    const int srow = tid >> 1, shalf = tid & 1;

    f32x4 acc[4][4];
#pragma unroll
    for (int m = 0; m < 4; m++)
#pragma unroll
        for (int n = 0; n < 4; n++)
#pragma unroll
            for (int r = 0; r < 4; r++) acc[m][n][r] = 0.f;

    for (int k0 = 0; k0 < K; k0 += 32) {
        __syncthreads();
        if (AF32) {
            const float* A = (const float*)Ap;
            const float* src = A + (size_t)(m0 + srow) * K + k0 + shalf * 16;
#pragma unroll
            for (int i = 0; i < 4; i++) {
                float4 f = ((const float4*)src)[i];
                ushort4 h;
                h.x = f2bf(f.x); h.y = f2bf(f.y); h.z = f2bf(f.z); h.w = f2bf(f.w);
                *(ushort4*)&lA[srow][shalf * 16 + i * 4] = h;
            }
        } else {
            const unsigned short* A = (const unsigned short*)Ap;
            const unsigned short* src = A + (size_t)(m0 + srow) * K + k0 + shalf * 16;
            *(uint4*)&lA[srow][shalf * 16] = *(const uint4*)src;
            *(uint4*)&lA[srow][shalf * 16 + 8] = *(const uint4*)(src + 8);
        }
        {
            const unsigned short* src = Bt + (size_t)(n0 + srow) * K + k0 + shalf * 16;
            *(uint4*)&lB[srow][shalf * 16] = *(const uint4*)src;
            *(uint4*)&lB[srow][shalf * 16 + 8] = *(const uint4*)(src + 8);
        }
        __syncthreads();

        bf16x8 a[4], b[4];
#pragma unroll
        for (int m = 0; m < 4; m++) a[m] = *(const bf16x8*)&lA[wr * 64 + m * 16 + fr][fq * 8];
#pragma unroll
        for (int n = 0; n < 4; n++) b[n] = *(const bf16x8*)&lB[wc * 64 + n * 16 + fr][fq * 8];
#pragma unroll
        for (int m = 0; m < 4; m++)
#pragma unroll
            for (int n = 0; n < 4; n++)
                acc[m][n] = __builtin_amdgcn_mfma_f32_16x16x32_bf16(a[m], b[n], acc[m][n], 0, 0, 0);
    }

#pragma unroll
    for (int m = 0; m < 4; m++) {
#pragma unroll
        for (int n = 0; n < 4; n++) {
#pragma unroll
            for (int r = 0; r < 4; r++) {
                const int row = m0 + wr * 64 + m * 16 + fq * 4 + r;
                const int col = n0 + wc * 64 + n * 16 + fr;
                const float v = acc[m][n][r] + bias[col];
                if (OUTMODE == 0) {
                    const int bb = row >> 11, t = row & 2047;
                    const int sec = col >> 10, cc = col & 1023;
                    const int h = cc >> 6, d = cc & 63;
                    unsigned short* dst = (sec == 0) ? Qo : ((sec == 1) ? Ko : Vo);
                    dst[(((size_t)(bb * 16 + h) * 2048 + t) << 6) + d] = f2bf(v);
                } else {
                    Cf[(size_t)row * N + col] = v;
                }
            }
        }
    }
}

// ---------------------------------------------------------------------------
// Causal flash attention.  Q,K,V bf16 [B*H, T, D=64] -> O bf16 [B, T, H*64].
// Block: 256 thr (4 waves), 128 q-rows per block (32 per wave), KV tiles of 64.
// ---------------------------------------------------------------------------
__global__ __launch_bounds__(256) void attn_kernel(const unsigned short* __restrict__ Q,
                                                   const unsigned short* __restrict__ Kg,
                                                   const unsigned short* __restrict__ V,
                                                   unsigned short* __restrict__ O) {
    __shared__ __align__(16) unsigned short lK[64][72];    // padded: 144B row stride
    __shared__ __align__(16) unsigned short lVt[64][72];   // V transposed: [d][kcol]
    __shared__ __align__(16) unsigned short lP[4][32][72]; // wave-private P scratch

    const int tid = threadIdx.x;
    const int lane = tid & 63, wid = tid >> 6;
    const int fr = lane & 15, fq = lane >> 4;
    const int bh = blockIdx.y;
    const int qb0 = blockIdx.x * 128;
    const size_t base = (size_t)bh * 2048 * 64;
    const unsigned short* Qp = Q + base;
    const unsigned short* Kp = Kg + base;
    const unsigned short* Vp = V + base;

    const int q0 = qb0 + wid * 32;
    bf16x8 qa[2][2];
#pragma unroll
    for (int m = 0; m < 2; m++)
#pragma unroll
        for (int kf = 0; kf < 2; kf++)
            qa[m][kf] = *(const bf16x8*)&Qp[(size_t)(q0 + m * 16 + fr) * 64 + kf * 32 + fq * 8];

    f32x4 o[2][4];
    float mrun[2][4], lrun[2][4];
#pragma unroll
    for (int m = 0; m < 2; m++)
#pragma unroll
        for (int r = 0; r < 4; r++) {
            mrun[m][r] = -__builtin_inff();
            lrun[m][r] = 0.f;
#pragma unroll
            for (int n = 0; n < 4; n++) o[m][n][r] = 0.f;
        }

    const int srow = tid >> 2, sc0 = (tid & 3) * 16;
    const int nt = (qb0 + 128) >> 6;
    const float scale = 0.125f;  // 1/sqrt(64)

    for (int kt = 0; kt < nt; kt++) {
        const int kt0 = kt << 6;
        __syncthreads();
        {
            const unsigned short* sk = Kp + (size_t)(kt0 + srow) * 64 + sc0;
            *(uint4*)&lK[srow][sc0] = *(const uint4*)sk;
            *(uint4*)&lK[srow][sc0 + 8] = *(const uint4*)(sk + 8);
            const unsigned short* sv = Vp + (size_t)(kt0 + srow) * 64 + sc0;
            unsigned short e[16];
            *(uint4*)&e[0] = *(const uint4*)sv;
            *(uint4*)&e[8] = *(const uint4*)(sv + 8);
#pragma unroll
            for (int j = 0; j < 16; j++) lVt[sc0 + j][srow] = e[j];
        }
        __syncthreads();

        // S = Q K^T
        f32x4 s[2][4];
#pragma unroll
        for (int m = 0; m < 2; m++)
#pragma unroll
            for (int n = 0; n < 4; n++)
#pragma unroll
                for (int r = 0; r < 4; r++) s[m][n][r] = 0.f;
#pragma unroll
        for (int n = 0; n < 4; n++)
#pragma unroll
            for (int kf = 0; kf < 2; kf++) {
                bf16x8 kb = *(const bf16x8*)&lK[n * 16 + fr][kf * 32 + fq * 8];
#pragma unroll
                for (int m = 0; m < 2; m++)
                    s[m][n] = __builtin_amdgcn_mfma_f32_16x16x32_bf16(qa[m][kf], kb, s[m][n], 0, 0, 0);
            }

        // online softmax (wave-parallel: reduce over the 16-lane fragment group)
#pragma unroll
        for (int m = 0; m < 2; m++) {
#pragma unroll
            for (int r = 0; r < 4; r++) {
                const int rg = q0 + m * 16 + fq * 4 + r;
                float rowmax = -3.0e38f;
#pragma unroll
                for (int n = 0; n < 4; n++) {
                    const int cg = kt0 + n * 16 + fr;
                    float sv = s[m][n][r] * scale;
                    sv = (cg > rg) ? -__builtin_inff() : sv;
                    s[m][n][r] = sv;
                    rowmax = fmaxf(rowmax, sv);
                }
                rowmax = fmaxf(rowmax, __shfl_xor(rowmax, 1));
                rowmax = fmaxf(rowmax, __shfl_xor(rowmax, 2));
                rowmax = fmaxf(rowmax, __shfl_xor(rowmax, 4));
                rowmax = fmaxf(rowmax, __shfl_xor(rowmax, 8));
                const float mnew = fmaxf(mrun[m][r], rowmax);
                const float alpha = __expf(mrun[m][r] - mnew);
                float rsum = 0.f;
#pragma unroll
                for (int n = 0; n < 4; n++) {
                    const float p = __expf(s[m][n][r] - mnew);
                    s[m][n][r] = p;
                    rsum += p;
                }
                rsum += __shfl_xor(rsum, 1);
                rsum += __shfl_xor(rsum, 2);
                rsum += __shfl_xor(rsum, 4);
                rsum += __shfl_xor(rsum, 8);
                mrun[m][r] = mnew;
                lrun[m][r] = lrun[m][r] * alpha + rsum;
#pragma unroll
                for (int n = 0; n < 4; n++) {
                    o[m][n][r] *= alpha;
                    lP[wid][m * 16 + fq * 4 + r][n * 16 + fr] = f2bf(s[m][n][r]);
                }
            }
        }

        // O += P V   (P re-read from LDS in A-fragment layout)
#pragma unroll
        for (int m = 0; m < 2; m++)
#pragma unroll
            for (int kf = 0; kf < 2; kf++) {
                bf16x8 pa = *(const bf16x8*)&lP[wid][m * 16 + fr][kf * 32 + fq * 8];
#pragma unroll
                for (int n = 0; n < 4; n++) {
                    bf16x8 vb = *(const bf16x8*)&lVt[n * 16 + fr][kf * 32 + fq * 8];
                    o[m][n] = __builtin_amdgcn_mfma_f32_16x16x32_bf16(pa, vb, o[m][n], 0, 0, 0);
                }
            }
    }

    // epilogue: O/l -> [B, T, H*64] bf16
    const int bb = bh >> 4, hh = bh & 15;
#pragma unroll
    for (int m = 0; m < 2; m++)
#pragma unroll
        for (int r = 0; r < 4; r++) {
            const float inv = 1.f / lrun[m][r];
            const int rg = q0 + m * 16 + fq * 4 + r;
#pragma unroll
            for (int n = 0; n < 4; n++) {
                const int d = n * 16 + fr;
                O[((size_t)(bb * 2048 + rg)) * 1024 + hh * 64 + d] = f2bf(o[m][n][r] * inv);
            }
        }
}

// ---------------------------------------------------------------------------
extern "C" void kernel_launch(void* const* d_in, const int* in_sizes, int n_in,
                              void* d_out, int out_size, void* d_ws, size_t ws_size,
                              hipStream_t stream) {
    const float* x      = (const float*)d_in[0];
    const float* w_qkv  = (const float*)d_in[1];
    const float* b_qkv  = (const float*)d_in[2];
    const float* w_proj = (const float*)d_in[3];
    const float* b_proj = (const float*)d_in[4];
    float* out = (float*)d_out;

    unsigned short* ws = (unsigned short*)d_ws;
    unsigned short* wqkvT  = ws;                       // 3072*1024
    unsigned short* wprojT = wqkvT + 3072 * 1024;      // 1024*1024
    unsigned short* Qb     = wprojT + 1024 * 1024;     // 32*2048*64 each
    unsigned short* Kb     = Qb + 32 * 2048 * 64;
    unsigned short* Vb     = Kb + 32 * 2048 * 64;
    unsigned short* attnO  = Vb + 32 * 2048 * 64;      // 4096*1024

    transpose_w<<<dim3(96, 32), dim3(32, 8), 0, stream>>>(w_qkv, wqkvT, 1024, 3072);
    transpose_w<<<dim3(32, 32), dim3(32, 8), 0, stream>>>(w_proj, wprojT, 1024, 1024);

    gemm_bt_kernel<true, 0><<<dim3(24, 32), 256, 0, stream>>>(
        (const void*)x, wqkvT, b_qkv, nullptr, Qb, Kb, Vb, 4096, 3072, 1024);

    attn_kernel<<<dim3(16, 32), 256, 0, stream>>>(Qb, Kb, Vb, attnO);

    gemm_bt_kernel<false, 1><<<dim3(8, 32), 256, 0, stream>>>(
        (const void*)attnO, wprojT, b_proj, out, nullptr, nullptr, nullptr, 4096, 1024, 1024);
}

// Round 2
// 158.881 us; speedup vs baseline: 1.6527x; 1.6527x over previous
//
#include <hip/hip_runtime.h>

typedef short bf16x8 __attribute__((ext_vector_type(8)));
typedef float f32x4 __attribute__((ext_vector_type(4)));
typedef unsigned short u16;
typedef unsigned short u16x8 __attribute__((ext_vector_type(8)));

__device__ __forceinline__ u16 f2bf(float f) {
    union { float f; unsigned u; } v; v.f = f;
    unsigned r = v.u + 0x7fffu + ((v.u >> 16) & 1u);
    return (u16)(r >> 16);
}

// async global->LDS, 16B per lane. lds base must be wave-uniform (HW adds lane*16).
__device__ __forceinline__ void gld_lds16(const void* g, void* l) {
    __builtin_amdgcn_global_load_lds(
        (const __attribute__((address_space(1))) void*)g,
        (__attribute__((address_space(3))) void*)l, 16, 0, 0);
}

// ---------------------------------------------------------------------------
// x fp32 -> bf16, 8 elems/thread
// ---------------------------------------------------------------------------
__global__ __launch_bounds__(256) void x_to_bf16(const float* __restrict__ in,
                                                 u16* __restrict__ out) {
    const int i = blockIdx.x * 256 + threadIdx.x;
    float4 a = ((const float4*)in)[i * 2];
    float4 b = ((const float4*)in)[i * 2 + 1];
    u16x8 h;
    h[0] = f2bf(a.x); h[1] = f2bf(a.y); h[2] = f2bf(a.z); h[3] = f2bf(a.w);
    h[4] = f2bf(b.x); h[5] = f2bf(b.y); h[6] = f2bf(b.z); h[7] = f2bf(b.w);
    *(u16x8*)(out + (size_t)i * 8) = h;
}

// ---------------------------------------------------------------------------
// Transpose + fp32->bf16 convert:  in[K][N] fp32  ->  out[N][K] bf16
// ---------------------------------------------------------------------------
__global__ __launch_bounds__(256) void transpose_w(const float* __restrict__ in,
                                                   u16* __restrict__ out,
                                                   int K, int N) {
    __shared__ float tile[32][33];
    const int n0 = blockIdx.x * 32, k0 = blockIdx.y * 32;
    const int tx = threadIdx.x, ty = threadIdx.y;
#pragma unroll
    for (int i = 0; i < 32; i += 8)
        tile[ty + i][tx] = in[(size_t)(k0 + ty + i) * N + n0 + tx];
    __syncthreads();
#pragma unroll
    for (int i = 0; i < 32; i += 8)
        out[(size_t)(n0 + ty + i) * K + k0 + tx] = f2bf(tile[tx][ty + i]);
}

// ---------------------------------------------------------------------------
// GEMM (m97 structure): C[M,N] = A[M,K](bf16) * Bt[N,K]^T + bias
// 128x128 tile, 4 waves (2x2 of 64x64), BK=32, linear LDS + global_load_lds x16.
// OUTMODE 0: scatter Q (pre-scaled by 0.125*log2e) / K as [B,H,T,D],
//            V transposed as [B,H,D,T].  OUTMODE 1: fp32 C + bias.
// ---------------------------------------------------------------------------
#define QSCALE 0.180336880f  // 0.125 * log2(e)

template <int OUTMODE>
__global__ __launch_bounds__(256) void gemm_m97(
    const u16* __restrict__ A, const u16* __restrict__ Bt,
    const float* __restrict__ bias, float* __restrict__ Cf,
    u16* __restrict__ Qo, u16* __restrict__ Ko, u16* __restrict__ Vt,
    int M, int N, int K) {
    __shared__ __align__(16) u16 lA[128 * 32];
    __shared__ __align__(16) u16 lB[128 * 32];

    const int tid = threadIdx.x;
    const int lane = tid & 63, wid = tid >> 6;
    const int wr = wid >> 1, wc = wid & 1;
    const int fr = lane & 15, fq = lane >> 4;
    const int m0 = blockIdx.y * 128, n0 = blockIdx.x * 128;

    // staging: thread t covers 16B at row=t>>2, kquarter=t&3 (linear LDS order)
    const u16* gA = A + (size_t)(m0 + (tid >> 2)) * K + (tid & 3) * 8;
    const u16* gB = Bt + (size_t)(n0 + (tid >> 2)) * K + (tid & 3) * 8;
    u16* lAw = lA + wid * 512;  // wave-uniform LDS base (bytes: wid*1024)
    u16* lBw = lB + wid * 512;

    f32x4 acc[4][4];
#pragma unroll
    for (int m = 0; m < 4; m++)
#pragma unroll
        for (int n = 0; n < 4; n++)
#pragma unroll
            for (int r = 0; r < 4; r++) acc[m][n][r] = 0.f;

    for (int k0 = 0; k0 < K; k0 += 32) {
        __syncthreads();
        gld_lds16(gA + k0, lAw);
        gld_lds16(gA + (size_t)64 * K + k0, lAw + 2048);
        gld_lds16(gB + k0, lBw);
        gld_lds16(gB + (size_t)64 * K + k0, lBw + 2048);
        __syncthreads();

        bf16x8 a[4], b[4];
#pragma unroll
        for (int m = 0; m < 4; m++)
            a[m] = *(const bf16x8*)&lA[(wr * 64 + m * 16 + fr) * 32 + fq * 8];
#pragma unroll
        for (int n = 0; n < 4; n++)
            b[n] = *(const bf16x8*)&lB[(wc * 64 + n * 16 + fr) * 32 + fq * 8];
#pragma unroll
        for (int m = 0; m < 4; m++)
#pragma unroll
            for (int n = 0; n < 4; n++)
                acc[m][n] = __builtin_amdgcn_mfma_f32_16x16x32_bf16(a[m], b[n], acc[m][n], 0, 0, 0);
    }

#pragma unroll
    for (int m = 0; m < 4; m++) {
#pragma unroll
        for (int n = 0; n < 4; n++) {
#pragma unroll
            for (int r = 0; r < 4; r++) {
                const int row = m0 + wr * 64 + m * 16 + fq * 4 + r;
                const int col = n0 + wc * 64 + n * 16 + fr;
                const float v = acc[m][n][r] + bias[col];
                if (OUTMODE == 0) {
                    const int bb = row >> 11, t = row & 2047;
                    const int sec = col >> 10, cc = col & 1023;
                    const int h = cc >> 6, d = cc & 63;
                    if (sec == 0)
                        Qo[(((size_t)(bb * 16 + h) * 2048 + t) << 6) + d] = f2bf(v * QSCALE);
                    else if (sec == 1)
                        Ko[(((size_t)(bb * 16 + h) * 2048 + t) << 6) + d] = f2bf(v);
                    else
                        Vt[(((size_t)(bb * 16 + h) * 64 + d) << 11) + t] = f2bf(v);
                } else {
                    Cf[(size_t)row * N + col] = v;
                }
            }
        }
    }
}

// ---------------------------------------------------------------------------
// Causal flash attention. Q pre-scaled (exp2 domain), V pre-transposed.
// Q,K bf16 [BH, T, 64]; Vt bf16 [BH, 64, T]; O bf16 [B, T, H*64].
// Block: 256 thr (4 waves), 64 q-rows (16 per wave), KV tiles of 64.
// Grid: 1024 1D, heaviest q-tiles first.
// ---------------------------------------------------------------------------
__global__ __launch_bounds__(256) void attn_kernel(const u16* __restrict__ Q,
                                                   const u16* __restrict__ Kg,
                                                   const u16* __restrict__ Vt,
                                                   u16* __restrict__ O) {
    __shared__ __align__(16) u16 lK[64][72];
    __shared__ __align__(16) u16 lV[64][72];    // V^T tile: [d][k]
    __shared__ __align__(16) u16 lP[4][16][68]; // wave-private P

    const int tid = threadIdx.x;
    const int lane = tid & 63, wid = tid >> 6;
    const int fr = lane & 15, fq = lane >> 4;
    const int bh = blockIdx.x & 31;
    const int qi = 31 - (blockIdx.x >> 5);  // heavy blocks first
    const int qb0 = qi * 64;
    const size_t base = (size_t)bh * (2048 * 64);
    const u16* Qp = Q + base;
    const u16* Kp = Kg + base;
    const u16* Vp = Vt + base;  // [64][2048]

    const int q0 = qb0 + wid * 16;
    bf16x8 qa[2];
#pragma unroll
    for (int kf = 0; kf < 2; kf++)
        qa[kf] = *(const bf16x8*)&Qp[(size_t)(q0 + fr) * 64 + kf * 32 + fq * 8];

    f32x4 o[4];
    float mrun[4], lrun[4];
#pragma unroll
    for (int r = 0; r < 4; r++) {
        mrun[r] = -__builtin_inff();
        lrun[r] = 0.f;
#pragma unroll
        for (int n = 0; n < 4; n++) o[n][r] = 0.f;
    }

    const int srow = tid >> 2, sc0 = (tid & 3) * 16;
    const int nt = qi + 1;

    for (int kt = 0; kt < nt; kt++) {
        const int kt0 = kt << 6;
        __syncthreads();
        {
            const u16* sk = Kp + (size_t)(kt0 + srow) * 64 + sc0;
            *(uint4*)&lK[srow][sc0] = *(const uint4*)sk;
            *(uint4*)&lK[srow][sc0 + 8] = *(const uint4*)(sk + 8);
            const u16* sv = Vp + ((size_t)srow << 11) + kt0 + sc0;
            *(uint4*)&lV[srow][sc0] = *(const uint4*)sv;
            *(uint4*)&lV[srow][sc0 + 8] = *(const uint4*)(sv + 8);
        }
        __syncthreads();

        // S = Q K^T  (log2 domain; Q pre-scaled)
        f32x4 s[4];
#pragma unroll
        for (int n = 0; n < 4; n++)
#pragma unroll
            for (int r = 0; r < 4; r++) s[n][r] = 0.f;
#pragma unroll
        for (int n = 0; n < 4; n++)
#pragma unroll
            for (int kf = 0; kf < 2; kf++) {
                bf16x8 kb = *(const bf16x8*)&lK[n * 16 + fr][kf * 32 + fq * 8];
                s[n] = __builtin_amdgcn_mfma_f32_16x16x32_bf16(qa[kf], kb, s[n], 0, 0, 0);
            }

        const bool diag = (kt == nt - 1);  // only the diagonal tile needs masking
#pragma unroll
        for (int r = 0; r < 4; r++) {
            const int rg = q0 + fq * 4 + r;
            float rowmax = -3.0e38f;
#pragma unroll
            for (int n = 0; n < 4; n++) {
                float sv = s[n][r];
                if (diag && (kt0 + n * 16 + fr > rg)) sv = -__builtin_inff();
                s[n][r] = sv;
                rowmax = fmaxf(rowmax, sv);
            }
            rowmax = fmaxf(rowmax, __shfl_xor(rowmax, 1));
            rowmax = fmaxf(rowmax, __shfl_xor(rowmax, 2));
            rowmax = fmaxf(rowmax, __shfl_xor(rowmax, 4));
            rowmax = fmaxf(rowmax, __shfl_xor(rowmax, 8));
            const float mnew = fmaxf(mrun[r], rowmax);
            const float alpha = exp2f(mrun[r] - mnew);
            float rsum = 0.f;
#pragma unroll
            for (int n = 0; n < 4; n++) {
                const float p = exp2f(s[n][r] - mnew);
                s[n][r] = p;
                rsum += p;
            }
            rsum += __shfl_xor(rsum, 1);
            rsum += __shfl_xor(rsum, 2);
            rsum += __shfl_xor(rsum, 4);
            rsum += __shfl_xor(rsum, 8);
            mrun[r] = mnew;
            lrun[r] = lrun[r] * alpha + rsum;
#pragma unroll
            for (int n = 0; n < 4; n++) {
                o[n][r] *= alpha;
                lP[wid][fq * 4 + r][n * 16 + fr] = f2bf(s[n][r]);
            }
        }

        // O += P V  (P read back in A-fragment layout; V^T already in lV)
#pragma unroll
        for (int kf = 0; kf < 2; kf++) {
            bf16x8 pa = *(const bf16x8*)&lP[wid][fr][kf * 32 + fq * 8];
#pragma unroll
            for (int n = 0; n < 4; n++) {
                bf16x8 vb = *(const bf16x8*)&lV[n * 16 + fr][kf * 32 + fq * 8];
                o[n] = __builtin_amdgcn_mfma_f32_16x16x32_bf16(pa, vb, o[n], 0, 0, 0);
            }
        }
    }

    // epilogue: O/l -> [B, T, H*64] bf16
    const int bb = bh >> 4, hh = bh & 15;
#pragma unroll
    for (int r = 0; r < 4; r++) {
        const float inv = 1.f / lrun[r];
        const int rg = q0 + fq * 4 + r;
#pragma unroll
        for (int n = 0; n < 4; n++)
            O[((size_t)(bb * 2048 + rg)) * 1024 + hh * 64 + n * 16 + fr] = f2bf(o[n][r] * inv);
    }
}

// ---------------------------------------------------------------------------
extern "C" void kernel_launch(void* const* d_in, const int* in_sizes, int n_in,
                              void* d_out, int out_size, void* d_ws, size_t ws_size,
                              hipStream_t stream) {
    const float* x      = (const float*)d_in[0];
    const float* w_qkv  = (const float*)d_in[1];
    const float* b_qkv  = (const float*)d_in[2];
    const float* w_proj = (const float*)d_in[3];
    const float* b_proj = (const float*)d_in[4];
    float* out = (float*)d_out;

    u16* ws = (u16*)d_ws;
    u16* wqkvT  = ws;                      // 3072*1024
    u16* wprojT = wqkvT + 3072 * 1024;     // 1024*1024
    u16* Qb     = wprojT + 1024 * 1024;    // 32*2048*64
    u16* Kb     = Qb + 32 * 2048 * 64;
    u16* Vtb    = Kb + 32 * 2048 * 64;     // transposed V [BH,64,2048]
    u16* xb     = Vtb + 32 * 2048 * 64;    // x as bf16; reused as attnO
    u16* attnO  = xb;                      // alias (xb dead after gemm1)

    x_to_bf16<<<2048, 256, 0, stream>>>(x, xb);
    transpose_w<<<dim3(96, 32), dim3(32, 8), 0, stream>>>(w_qkv, wqkvT, 1024, 3072);
    transpose_w<<<dim3(32, 32), dim3(32, 8), 0, stream>>>(w_proj, wprojT, 1024, 1024);

    gemm_m97<0><<<dim3(24, 32), 256, 0, stream>>>(
        xb, wqkvT, b_qkv, nullptr, Qb, Kb, Vtb, 4096, 3072, 1024);

    attn_kernel<<<1024, 256, 0, stream>>>(Qb, Kb, Vtb, attnO);

    gemm_m97<1><<<dim3(8, 32), 256, 0, stream>>>(
        attnO, wprojT, b_proj, out, nullptr, nullptr, nullptr, 4096, 1024, 1024);
}